// Round 1
// baseline (20756.981 us; speedup 1.0000x reference)
//
#include <hip/hip_runtime.h>
#include <math.h>

#define BB 512
#define LC 128
#define LA 16
#define EE 300
#define HH 300
#define G4 1200
#define D2 600

__device__ __forceinline__ float sigf(float x){ return 1.0f/(1.0f+expf(-x)); }

// ---------------- lengths ----------------
__global__ void k_lengths(const int* __restrict__ traw, const int* __restrict__ tasp,
                          const int* __restrict__ tleft,
                          int* __restrict__ clen, int* __restrict__ alen, int* __restrict__ sstart){
  int b = blockIdx.x*blockDim.x + threadIdx.x;
  if (b >= BB) return;
  int c=0,a=0,l=0;
  for (int t=0;t<LC;t++) c += (traw[b*LC+t]!=0);
  for (int t=0;t<LA;t++) a += (tasp[b*LA+t]!=0);
  for (int t=0;t<LC;t++) l += (tleft[b*LC+t]!=0);
  clen[b]=c; alen[b]=a; sstart[b]=l;
}

// ---------------- fused BiLSTM recurrence ----------------
// 256 blocks: job = blockIdx&3 (0=ctx-fwd,1=ctx-bwd,2=asp-fwd,3=asp-bwd), 8 batch rows/block.
// job = bid&3 so each job maps to fixed XCDs (bid%8 in {j, j+4}) -> W slab stays L2-resident.
__launch_bounds__(512,1)
__global__ void k_lstm(const int* __restrict__ traw, const int* __restrict__ tasp,
                       const float* __restrict__ embed,
                       const float* __restrict__ cWif, const float* __restrict__ cWhf, const float* __restrict__ cbf,
                       const float* __restrict__ cWib, const float* __restrict__ cWhb, const float* __restrict__ cbb,
                       const float* __restrict__ aWif, const float* __restrict__ aWhf, const float* __restrict__ abf,
                       const float* __restrict__ aWib, const float* __restrict__ aWhb, const float* __restrict__ abb,
                       const int* __restrict__ clen, const int* __restrict__ alen, const int* __restrict__ sstart,
                       float* __restrict__ ctx_out, float* __restrict__ asp_out)
{
  const int tid = threadIdx.x;
  const int job = blockIdx.x & 3;
  const int sub = blockIdx.x >> 2;
  const int row0 = sub*8;

  const int* tokp; int T; const int* lenp;
  const float *Wih, *Whh, *bias; float* outb; int coloff, bwd, win;
  if (job==0){ tokp=traw; T=LC; lenp=clen; Wih=cWif; Whh=cWhf; bias=cbf; outb=ctx_out; coloff=0;   bwd=0; win=1; }
  else if (job==1){ tokp=traw; T=LC; lenp=clen; Wih=cWib; Whh=cWhb; bias=cbb; outb=ctx_out; coloff=300; bwd=1; win=1; }
  else if (job==2){ tokp=tasp; T=LA; lenp=alen; Wih=aWif; Whh=aWhf; bias=abf; outb=asp_out; coloff=0;   bwd=0; win=0; }
  else            { tokp=tasp; T=LA; lenp=alen; Wih=aWib; Whh=aWhb; bias=abb; outb=asp_out; coloff=300; bwd=1; win=0; }

  __shared__ __align__(16) float xh[8][600];   // [x(300) | h(300)] per row
  __shared__ float cst[8][300];
  __shared__ float gs[8][1200];
  __shared__ int   tok[8][LC];
  __shared__ int   len_s[8];
  __shared__ float win_s[8], win_e[8], win_sl[8];

  for (int idx=tid; idx<8*T; idx+=512){ int r=idx/T, t=idx-r*T; tok[r][t]=tokp[(row0+r)*T+t]; }
  if (tid<8){
    int b=row0+tid; len_s[tid]=lenp[b];
    if (win){ float s=(float)sstart[b], a=(float)alen[b];
      win_s[tid]=s; win_e[tid]=s+a-1.0f; win_sl[tid]=(float)LC - a; }
    else { win_s[tid]=0.f; win_e[tid]=0.f; win_sl[tid]=1.f; }
  }
  for (int idx=tid; idx<2400; idx+=512){ int r=idx/300, d=idx-r*300; xh[r][300+d]=0.0f; cst[r][d]=0.0f; }
  __syncthreads();
  int maxl=0;
  #pragma unroll
  for (int r=0;r<8;r++) maxl = max(maxl, len_s[r]);

  for (int t=0;t<maxl;t++){
    // ---- stage x (gather embedding rows) ----
    for (int idx=tid; idx<2400; idx+=512){
      int r=idx/300, d=idx-r*300;
      int L=len_s[r];
      int ts = bwd ? ((t<L)?(L-1-t):t) : t;
      int tk = tok[r][ts];
      xh[r][d] = embed[(size_t)tk*EE + d];
    }
    __syncthreads();
    // ---- g = [x|h] * [Wih|Whh]^T + b ----
    {
      const int na = tid, nb = tid+512;
      float accA[8], accB[8];
      #pragma unroll
      for (int r=0;r<8;r++){accA[r]=0.f;accB[r]=0.f;}
      {
        const float4* WA=(const float4*)(Wih+(size_t)na*300);
        const float4* WB=(const float4*)(Wih+(size_t)nb*300);
        for (int k4=0;k4<75;k4++){
          float4 wa=WA[k4], wb=WB[k4];
          #pragma unroll
          for (int r=0;r<8;r++){
            const float4 xv=*(const float4*)&xh[r][4*k4];
            accA[r]=fmaf(wa.w,xv.w,fmaf(wa.z,xv.z,fmaf(wa.y,xv.y,fmaf(wa.x,xv.x,accA[r]))));
            accB[r]=fmaf(wb.w,xv.w,fmaf(wb.z,xv.z,fmaf(wb.y,xv.y,fmaf(wb.x,xv.x,accB[r]))));
          }
        }
      }
      {
        const float4* WA=(const float4*)(Whh+(size_t)na*300);
        const float4* WB=(const float4*)(Whh+(size_t)nb*300);
        for (int k4=0;k4<75;k4++){
          float4 wa=WA[k4], wb=WB[k4];
          #pragma unroll
          for (int r=0;r<8;r++){
            const float4 xv=*(const float4*)&xh[r][300+4*k4];
            accA[r]=fmaf(wa.w,xv.w,fmaf(wa.z,xv.z,fmaf(wa.y,xv.y,fmaf(wa.x,xv.x,accA[r]))));
            accB[r]=fmaf(wb.w,xv.w,fmaf(wb.z,xv.z,fmaf(wb.y,xv.y,fmaf(wb.x,xv.x,accB[r]))));
          }
        }
      }
      float ba=bias[na], bb2=bias[nb];
      #pragma unroll
      for (int r=0;r<8;r++){ gs[r][na]=accA[r]+ba; gs[r][nb]=accB[r]+bb2; }
      if (tid<176){
        const int nc = 1024+tid;
        float accC[8];
        #pragma unroll
        for (int r=0;r<8;r++) accC[r]=0.f;
        {
          const float4* WC=(const float4*)(Wih+(size_t)nc*300);
          for (int k4=0;k4<75;k4++){
            float4 wc=WC[k4];
            #pragma unroll
            for (int r=0;r<8;r++){
              const float4 xv=*(const float4*)&xh[r][4*k4];
              accC[r]=fmaf(wc.w,xv.w,fmaf(wc.z,xv.z,fmaf(wc.y,xv.y,fmaf(wc.x,xv.x,accC[r]))));
            }
          }
        }
        {
          const float4* WC=(const float4*)(Whh+(size_t)nc*300);
          for (int k4=0;k4<75;k4++){
            float4 wc=WC[k4];
            #pragma unroll
            for (int r=0;r<8;r++){
              const float4 xv=*(const float4*)&xh[r][300+4*k4];
              accC[r]=fmaf(wc.w,xv.w,fmaf(wc.z,xv.z,fmaf(wc.y,xv.y,fmaf(wc.x,xv.x,accC[r]))));
            }
          }
        }
        float bc=bias[nc];
        #pragma unroll
        for (int r=0;r<8;r++) gs[r][nc]=accC[r]+bc;
      }
    }
    __syncthreads();
    // ---- gate nonlinearities, state update, masked/windowed store ----
    for (int idx=tid; idx<2400; idx+=512){
      int r=idx/300, d=idx-r*300;
      int L=len_s[r];
      if (t<L){
        float gi=gs[r][d], gf=gs[r][300+d], gg=gs[r][600+d], go=gs[r][900+d];
        float cn = sigf(gf)*cst[r][d] + sigf(gi)*tanhf(gg);
        float hn = sigf(go)*tanhf(cn);
        cst[r][d]=cn; xh[r][300+d]=hn;
        int tpos = bwd ? (L-1-t) : t;
        float wgt=1.0f;
        if (win){
          float jf=(float)tpos;
          float s=win_s[r], e=win_e[r], sl=win_sl[r];
          wgt = (jf<s)?(1.0f-(s-jf)/sl):((jf<=e)?0.0f:(1.0f-(jf-e)/sl));
        }
        outb[((size_t)(row0+r)*T+tpos)*(size_t)D2 + coloff + d] = hn*wgt;
      }
    }
    __syncthreads();
  }
}

// ---------------- pooling ----------------
__global__ void k_pool(const float* __restrict__ ctx_out, const float* __restrict__ asp_out,
                       const int* __restrict__ clen, const int* __restrict__ alen,
                       float* __restrict__ ctx_pool, float* __restrict__ asp_pool){
  const int b=blockIdx.x; const int tid=threadIdx.x;
  for (int d=tid; d<D2; d+=blockDim.x){
    float s=0.f;
    for (int t=0;t<LC;t++) s+=ctx_out[((size_t)b*LC+t)*D2+d];
    ctx_pool[(size_t)b*D2+d]=s/(float)clen[b];
    float s2=0.f;
    for (int t=0;t<LA;t++) s2+=asp_out[((size_t)b*LA+t)*D2+d];
    asp_pool[(size_t)b*D2+d]=s2/(float)alen[b];
  }
}

// ---------------- v1 = w_a2c @ asp_pool ; v2 = w_c2a @ ctx_pool ----------------
__global__ void k_v1v2(const float* __restrict__ w_a2c, const float* __restrict__ w_c2a,
                       const float* __restrict__ ctx_pool, const float* __restrict__ asp_pool,
                       float* __restrict__ v1, float* __restrict__ v2){
  const int b=blockIdx.x; const int tid=threadIdx.x;
  __shared__ __align__(16) float ap[600];
  __shared__ __align__(16) float cp[600];
  for (int d=tid;d<600;d+=256){ ap[d]=asp_pool[(size_t)b*D2+d]; cp[d]=ctx_pool[(size_t)b*D2+d]; }
  __syncthreads();
  for (int d=tid;d<600;d+=256){
    const float4* ra=(const float4*)(w_a2c+(size_t)d*600);
    const float4* rc=(const float4*)(w_c2a+(size_t)d*600);
    float s1=0.f,s2=0.f;
    for (int e4=0;e4<150;e4++){
      float4 wa=ra[e4], wc=rc[e4];
      const float4 av=*(const float4*)&ap[4*e4];
      const float4 cv=*(const float4*)&cp[4*e4];
      s1 = fmaf(wa.w,av.w,fmaf(wa.z,av.z,fmaf(wa.y,av.y,fmaf(wa.x,av.x,s1))));
      s2 = fmaf(wc.w,cv.w,fmaf(wc.z,cv.z,fmaf(wc.y,cv.y,fmaf(wc.x,cv.x,s2))));
    }
    v1[(size_t)b*D2+d]=s1; v2[(size_t)b*D2+d]=s2;
  }
}

// ---------------- fused attention + head, one block per batch row ----------------
__launch_bounds__(256,2)
__global__ void k_attn(const float* __restrict__ ctx_out, const float* __restrict__ asp_out,
                       const float* __restrict__ v1, const float* __restrict__ v2,
                       const float* __restrict__ w_u, const float* __restrict__ dW,
                       const float* __restrict__ db, float* __restrict__ out)
{
  const int b = blockIdx.x;
  const int tid = threadIdx.x;
  const int wv = tid>>6, lane = tid&63;

  __shared__ float asp[16][600];
  __shared__ float w1s[600], w3s[600], v1s[600], v2s[600];
  __shared__ float u2s[16], m2w[4][16];
  __shared__ float m1s[128], s1s[128];
  __shared__ float alph[128], a1s[128];
  __shared__ float bet[16], a2s[16], m2f[16], s2s[16];
  __shared__ float red[256];
  __shared__ float feat[2400];

  for (int idx=tid; idx<16*600; idx+=256){
    int j=idx/600, d=idx-j*600;
    asp[j][d]=asp_out[((size_t)b*LA+j)*D2+d];
  }
  for (int d=tid; d<600; d+=256){
    w1s[d]=w_u[d]; w3s[d]=w_u[1200+d];
    v1s[d]=v1[(size_t)b*D2+d]; v2s[d]=v2[(size_t)b*D2+d];
  }
  if (tid<64) m2w[tid>>4][tid&15] = -1e30f;
  __syncthreads();
  if (tid<16){
    float s=0.f;
    for (int d=0;d<600;d++) s += asp[tid][d]*w_u[600+d];
    u2s[tid]=s;
  }
  __syncthreads();

  // ---- pass A: per ctx position i -> u1, s1, tri-row; track row/col maxes ----
  float m2p[16];
  #pragma unroll
  for (int j=0;j<16;j++) m2p[j]=-1e30f;

  for (int i=wv; i<LC; i+=4){
    const float* crow = ctx_out + ((size_t)b*LC+i)*D2;
    float u1p=0.f, s1p=0.f, accj[16];
    #pragma unroll
    for (int j=0;j<16;j++) accj[j]=0.f;
    for (int m=0;m<10;m++){
      int d = lane + m*64;
      if (d<600){
        float v = crow[d];
        u1p = fmaf(v,w1s[d],u1p);
        s1p = fmaf(v,v1s[d],s1p);
        float cw = v*w3s[d];
        #pragma unroll
        for (int j=0;j<16;j++) accj[j] = fmaf(cw,asp[j][d],accj[j]);
      }
    }
    #pragma unroll
    for (int off=32; off>0; off>>=1){
      u1p += __shfl_xor(u1p,off);
      s1p += __shfl_xor(s1p,off);
      #pragma unroll
      for (int j=0;j<16;j++) accj[j] += __shfl_xor(accj[j],off);
    }
    float mj=-1e30f;
    #pragma unroll
    for (int j=0;j<16;j++){
      float a = u2s[j]+accj[j];
      mj = fmaxf(mj,a);
      m2p[j] = fmaxf(m2p[j], u1p+accj[j]);
    }
    if (lane==0){ m1s[i]=u1p+mj; s1s[i]=s1p; }
  }
  if (lane<16) m2w[wv][lane]=m2p[lane];
  __syncthreads();

  // ---- softmax over i of m1s -> alph ; of s1s -> a1s ----
  {
    float x1 = (tid<128)? m1s[tid] : -1e30f;
    red[tid]=x1; __syncthreads();
    for (int s=128;s>0;s>>=1){ if (tid<s) red[tid]=fmaxf(red[tid],red[tid+s]); __syncthreads(); }
    float M1=red[0]; __syncthreads();
    float e1=(tid<128)?expf(x1-M1):0.f;
    red[tid]=e1; __syncthreads();
    for (int s=128;s>0;s>>=1){ if (tid<s) red[tid]+=red[tid+s]; __syncthreads(); }
    float S1=red[0]; __syncthreads();
    if (tid<128) alph[tid]=e1/S1;

    float x2 = (tid<128)? s1s[tid] : -1e30f;
    red[tid]=x2; __syncthreads();
    for (int s=128;s>0;s>>=1){ if (tid<s) red[tid]=fmaxf(red[tid],red[tid+s]); __syncthreads(); }
    float M2=red[0]; __syncthreads();
    float e2=(tid<128)?expf(x2-M2):0.f;
    red[tid]=e2; __syncthreads();
    for (int s=128;s>0;s>>=1){ if (tid<s) red[tid]+=red[tid+s]; __syncthreads(); }
    float S2=red[0]; __syncthreads();
    if (tid<128) a1s[tid]=e2/S2;
  }

  // ---- aspect-side scores ----
  if (tid<16){
    float m=-1e30f;
    #pragma unroll
    for (int w=0;w<4;w++) m=fmaxf(m,m2w[w][tid]);
    m2f[tid]=u2s[tid]+m;
    float s=0.f;
    for (int d=0;d<600;d++) s = fmaf(asp[tid][d],v2s[d],s);
    s2s[tid]=s;
  }
  __syncthreads();
  if (tid==0){
    float M=-1e30f,S=0.f;
    for (int j=0;j<16;j++) M=fmaxf(M,m2f[j]);
    for (int j=0;j<16;j++){ float e=expf(m2f[j]-M); bet[j]=e; S+=e; }
    for (int j=0;j<16;j++) bet[j]/=S;
    M=-1e30f;S=0.f;
    for (int j=0;j<16;j++) M=fmaxf(M,s2s[j]);
    for (int j=0;j<16;j++){ float e=expf(s2s[j]-M); a2s[j]=e; S+=e; }
    for (int j=0;j<16;j++) a2s[j]/=S;
  }
  __syncthreads();

  // ---- weighted sums -> feat ----
  {
    const bool has2 = (tid<88);
    float fa0=0,fa1=0,fa2=0, ca0=0,ca1=0,ca2=0;
    for (int i=0;i<LC;i++){
      float al=alph[i], aa=a1s[i];
      const float* crow = ctx_out + ((size_t)b*LC+i)*D2;
      float x0=crow[tid];      fa0=fmaf(al,x0,fa0); ca0=fmaf(aa,x0,ca0);
      float x1=crow[tid+256];  fa1=fmaf(al,x1,fa1); ca1=fmaf(aa,x1,ca1);
      if (has2){ float x2=crow[tid+512]; fa2=fmaf(al,x2,fa2); ca2=fmaf(aa,x2,ca2); }
    }
    feat[tid]=ca0;           feat[600+tid]=fa0;
    feat[tid+256]=ca1;       feat[600+tid+256]=fa1;
    if (has2){ feat[tid+512]=ca2; feat[600+tid+512]=fa2; }

    float fc0=0,fc1=0,fc2=0, cc0=0,cc1=0,cc2=0;
    for (int j=0;j<16;j++){
      float be=bet[j], a2=a2s[j];
      float x0=asp[j][tid];      fc0=fmaf(be,x0,fc0); cc0=fmaf(a2,x0,cc0);
      float x1=asp[j][tid+256];  fc1=fmaf(be,x1,fc1); cc1=fmaf(a2,x1,cc1);
      if (has2){ float x2=asp[j][tid+512]; fc2=fmaf(be,x2,fc2); cc2=fmaf(a2,x2,cc2); }
    }
    feat[1200+tid]=fc0;        feat[1800+tid]=cc0;
    feat[1200+tid+256]=fc1;    feat[1800+tid+256]=cc1;
    if (has2){ feat[1200+tid+512]=fc2; feat[1800+tid+512]=cc2; }
  }
  __syncthreads();

  // ---- out = feat @ dW^T + db ----
  {
    float p0=0,p1=0,p2=0;
    for (int e=tid;e<2400;e+=256){
      float f=feat[e];
      p0=fmaf(f,dW[e],p0); p1=fmaf(f,dW[2400+e],p1); p2=fmaf(f,dW[4800+e],p2);
    }
    red[tid]=p0; __syncthreads();
    for (int s=128;s>0;s>>=1){ if (tid<s) red[tid]+=red[tid+s]; __syncthreads(); }
    if (tid==0) out[b*3+0]=red[0]+db[0];
    __syncthreads();
    red[tid]=p1; __syncthreads();
    for (int s=128;s>0;s>>=1){ if (tid<s) red[tid]+=red[tid+s]; __syncthreads(); }
    if (tid==0) out[b*3+1]=red[0]+db[1];
    __syncthreads();
    red[tid]=p2; __syncthreads();
    for (int s=128;s>0;s>>=1){ if (tid<s) red[tid]+=red[tid+s]; __syncthreads(); }
    if (tid==0) out[b*3+2]=red[0]+db[2];
  }
}

extern "C" void kernel_launch(void* const* d_in, const int* in_sizes, int n_in,
                              void* d_out, int out_size, void* d_ws, size_t ws_size,
                              hipStream_t stream) {
  const int*   traw =(const int*)d_in[0];
  const int*   tasp =(const int*)d_in[1];
  const int*   tleft=(const int*)d_in[2];
  const float* embed=(const float*)d_in[3];
  const float* cWif=(const float*)d_in[4];
  const float* cWhf=(const float*)d_in[5];
  const float* cbf =(const float*)d_in[6];
  const float* cWib=(const float*)d_in[7];
  const float* cWhb=(const float*)d_in[8];
  const float* cbb =(const float*)d_in[9];
  const float* aWif=(const float*)d_in[10];
  const float* aWhf=(const float*)d_in[11];
  const float* abf =(const float*)d_in[12];
  const float* aWib=(const float*)d_in[13];
  const float* aWhb=(const float*)d_in[14];
  const float* abb =(const float*)d_in[15];
  const float* w_u =(const float*)d_in[16];
  const float* w_a2c=(const float*)d_in[17];
  const float* w_c2a=(const float*)d_in[18];
  const float* dW  =(const float*)d_in[19];
  const float* db  =(const float*)d_in[20];
  float* out = (float*)d_out;

  char* w = (char*)d_ws;
  size_t o = 0;
  float* ctx_out  = (float*)(w+o); o += (size_t)BB*LC*D2*4;   // 157,286,400
  float* asp_out  = (float*)(w+o); o += (size_t)BB*LA*D2*4;   //  19,660,800
  float* ctx_pool = (float*)(w+o); o += (size_t)BB*D2*4;
  float* asp_pool = (float*)(w+o); o += (size_t)BB*D2*4;
  float* v1       = (float*)(w+o); o += (size_t)BB*D2*4;
  float* v2       = (float*)(w+o); o += (size_t)BB*D2*4;
  int*   clen     = (int*)(w+o);   o += (size_t)BB*4;
  int*   alen_    = (int*)(w+o);   o += (size_t)BB*4;
  int*   sstart   = (int*)(w+o);   o += (size_t)BB*4;

  // zero ctx_out + asp_out (contiguous)
  hipMemsetAsync(ctx_out, 0, (size_t)BB*LC*D2*4 + (size_t)BB*LA*D2*4, stream);

  k_lengths<<<4,128,0,stream>>>(traw,tasp,tleft,clen,alen_,sstart);

  k_lstm<<<256,512,0,stream>>>(traw,tasp,embed,
                               cWif,cWhf,cbf,cWib,cWhb,cbb,
                               aWif,aWhf,abf,aWib,aWhb,abb,
                               clen,alen_,sstart,
                               ctx_out,asp_out);

  k_pool<<<512,256,0,stream>>>(ctx_out,asp_out,clen,alen_,ctx_pool,asp_pool);
  k_v1v2<<<512,256,0,stream>>>(w_a2c,w_c2a,ctx_pool,asp_pool,v1,v2);
  k_attn<<<512,256,0,stream>>>(ctx_out,asp_out,v1,v2,w_u,dW,db,out);
}

// Round 2
// 7435.919 us; speedup vs baseline: 2.7914x; 2.7914x over previous
//
#include <hip/hip_runtime.h>
#include <math.h>

#define BB 512
#define LC 128
#define LA 16
#define EE 300
#define HH 300
#define D2 600

__device__ __forceinline__ float sigf(float x){ return 1.0f/(1.0f+expf(-x)); }

// ---------------- lengths ----------------
__global__ void k_lengths(const int* __restrict__ traw, const int* __restrict__ tasp,
                          const int* __restrict__ tleft,
                          int* __restrict__ clen, int* __restrict__ alen, int* __restrict__ sstart){
  int b = blockIdx.x*blockDim.x + threadIdx.x;
  if (b >= BB) return;
  int c=0,a=0,l=0;
  for (int t=0;t<LC;t++) c += (traw[b*LC+t]!=0);
  for (int t=0;t<LA;t++) a += (tasp[b*LA+t]!=0);
  for (int t=0;t<LC;t++) l += (tleft[b*LC+t]!=0);
  clen[b]=c; alen[b]=a; sstart[b]=l;
}

// ---------------- weight transpose: W[1200][300] -> WT4[kq=75][n=1200][kk=4] ----------------
// mats: 0 cWif, 1 cWhf, 2 cWib, 3 cWhb, 4 aWif, 5 aWhf, 6 aWib, 7 aWhb
__global__ void k_prep(const float* __restrict__ cWif,const float* __restrict__ cWhf,
                       const float* __restrict__ cWib,const float* __restrict__ cWhb,
                       const float* __restrict__ aWif,const float* __restrict__ aWhf,
                       const float* __restrict__ aWib,const float* __restrict__ aWhb,
                       float* __restrict__ WT4){
  const int m = blockIdx.z;
  const float* src;
  switch(m){
    case 0: src=cWif; break; case 1: src=cWhf; break;
    case 2: src=cWib; break; case 3: src=cWhb; break;
    case 4: src=aWif; break; case 5: src=aWhf; break;
    case 6: src=aWib; break; default: src=aWhb; break;
  }
  int rem = blockIdx.x*blockDim.x + threadIdx.x;   // over 75*1200 = 90000 float4s
  if (rem >= 90000) return;
  int kq = rem/1200, n = rem - kq*1200;
  float4 v = *(const float4*)(src + (size_t)n*300 + kq*4);
  ((float4*)WT4)[(size_t)m*90000 + rem] = v;
}

// ---------------- coalesced K-loop core ----------------
// thread owns gate rows n0=tid, n1=tid+512, n2=tid+1024 (tid<176).
// W in k-packed layout; src is an LDS [8][300] buffer read as broadcast float4.
__device__ __forceinline__ void kloop8(const float (*__restrict__ src)[300],
                                       const float* __restrict__ W,
                                       float* a0, float* a1, float* a2,
                                       int n0, int n1, int n2, bool has3){
  const float4* Wp = (const float4*)W;
  for (int kq=0; kq<75; ++kq){
    float4 w0 = Wp[n0];
    float4 w1 = Wp[n1];
    #pragma unroll
    for (int r=0;r<8;r++){
      float4 h4 = *(const float4*)&src[r][4*kq];
      a0[r]=fmaf(w0.w,h4.w,fmaf(w0.z,h4.z,fmaf(w0.y,h4.y,fmaf(w0.x,h4.x,a0[r]))));
      a1[r]=fmaf(w1.w,h4.w,fmaf(w1.z,h4.z,fmaf(w1.y,h4.y,fmaf(w1.x,h4.x,a1[r]))));
    }
    if (has3){
      float4 w2 = Wp[n2];
      #pragma unroll
      for (int r=0;r<8;r++){
        float4 h4 = *(const float4*)&src[r][4*kq];
        a2[r]=fmaf(w2.w,h4.w,fmaf(w2.z,h4.z,fmaf(w2.y,h4.y,fmaf(w2.x,h4.x,a2[r]))));
      }
    }
    Wp += 1200;
  }
}

// ---------------- xg precompute (ctx only): xg[b][t][n] = sum_e emb[tok]*Wi[n][e] + b[n] ----------------
__launch_bounds__(512,1)
__global__ void k_xg(const int* __restrict__ traw, const float* __restrict__ embed,
                     const float* __restrict__ WT4,
                     const float* __restrict__ cbf, const float* __restrict__ cbb,
                     const int* __restrict__ clen,
                     float* __restrict__ xgcf, float* __restrict__ xgcb){
  const int bid = blockIdx.x;
  const int dir = bid & 1;            // 0 fwd, 1 bwd
  const int blkInJob = bid >> 1;      // 0..255
  const float* Wi = WT4 + (size_t)(dir?2:0)*360000;
  const float* bias = dir ? cbb : cbf;
  float* xg = dir ? xgcb : xgcf;
  const int tid = threadIdx.x;
  const int n0=tid, n1=tid+512, n2=tid+1024;
  const bool has3 = tid<176;

  __shared__ __align__(16) float emb16[16][300];
  __shared__ int tk[16];

  const float b0 = bias[n0], b1 = bias[n1], b2 = has3 ? bias[n2] : 0.f;

  for (int tile = blkInJob; tile < 4096; tile += 256){
    const int b = tile >> 3;
    const int t0 = (tile & 7)*16;
    const int len = clen[b];
    if (t0 >= len) continue;
    const int cnt = min(16, len - t0);
    if (tid < 16){
      int t = t0 + tid;
      int pos = dir ? (len-1-t) : t;
      tk[tid] = (tid < cnt) ? traw[b*LC + pos] : 0;
    }
    __syncthreads();
    for (int idx=tid; idx<cnt*300; idx+=512){
      int r = idx/300, e = idx - r*300;
      emb16[r][e] = embed[(size_t)tk[r]*EE + e];
    }
    __syncthreads();

    float a0[16], a1[16], a2[16];
    #pragma unroll
    for (int r=0;r<16;r++){ a0[r]=b0; a1[r]=b1; a2[r]=b2; }
    {
      const float4* Wp = (const float4*)Wi;
      for (int kq=0; kq<75; ++kq){
        float4 w0 = Wp[n0];
        float4 w1 = Wp[n1];
        #pragma unroll
        for (int r=0;r<16;r++){
          float4 h4 = *(const float4*)&emb16[r][4*kq];
          a0[r]=fmaf(w0.w,h4.w,fmaf(w0.z,h4.z,fmaf(w0.y,h4.y,fmaf(w0.x,h4.x,a0[r]))));
          a1[r]=fmaf(w1.w,h4.w,fmaf(w1.z,h4.z,fmaf(w1.y,h4.y,fmaf(w1.x,h4.x,a1[r]))));
        }
        if (has3){
          float4 w2 = Wp[n2];
          #pragma unroll
          for (int r=0;r<16;r++){
            float4 h4 = *(const float4*)&emb16[r][4*kq];
            a2[r]=fmaf(w2.w,h4.w,fmaf(w2.z,h4.z,fmaf(w2.y,h4.y,fmaf(w2.x,h4.x,a2[r]))));
          }
        }
        Wp += 1200;
      }
    }
    #pragma unroll
    for (int r=0;r<16;r++){
      if (r < cnt){
        size_t base = ((size_t)b*LC + t0 + r)*1200;
        xg[base+n0]=a0[r]; xg[base+n1]=a1[r];
        if (has3) xg[base+n2]=a2[r];
      }
    }
    __syncthreads();
  }
}

// ---------------- fused BiLSTM recurrence ----------------
// 256 blocks: job = bid&3 (ctx-f, ctx-b, asp-f, asp-b), 8 rows/block.
// bid%8 -> XCD mapping keeps each job's WhT slab (1.44MB) resident in one XCD's L2.
__launch_bounds__(512,1)
__global__ void k_rec(const int* __restrict__ traw, const int* __restrict__ tasp,
                      const float* __restrict__ embed,
                      const float* __restrict__ WT4,
                      const float* __restrict__ cbf, const float* __restrict__ cbb,
                      const float* __restrict__ abf, const float* __restrict__ abb,
                      const float* __restrict__ xgcf, const float* __restrict__ xgcb,
                      const int* __restrict__ clen, const int* __restrict__ alen,
                      const int* __restrict__ sstart,
                      float* __restrict__ ctx_out, float* __restrict__ asp_out, int use_xg)
{
  const int tid = threadIdx.x;
  const int job = blockIdx.x & 3;
  const int sub = blockIdx.x >> 2;
  const int row0 = sub*8;
  const int isCtx = (job < 2), bwd = (job & 1);
  const int T = isCtx ? LC : LA;
  const int* lenp = isCtx ? clen : alen;
  const int* tokp = isCtx ? traw : tasp;
  const float* Wi = WT4 + (size_t)(job*2)*360000;
  const float* Wh = Wi + 360000;
  const float* bias = (job==0)?cbf:(job==1)?cbb:(job==2)?abf:abb;
  float* outb = isCtx ? ctx_out : asp_out;
  const int coloff = bwd ? 300 : 0;
  const int fuseX = isCtx ? (!use_xg) : 1;           // asp always fused
  const float* xg = bwd ? xgcb : xgcf;

  __shared__ __align__(16) float hb[2][8][300];
  __shared__ __align__(16) float xb[8][300];
  __shared__ float gs[8][1200];
  __shared__ int  tok_s[8][LC];
  __shared__ int  len_s[8];
  __shared__ float wins[8], wine[8], winl[8];

  if (fuseX){
    for (int idx=tid; idx<8*T; idx+=512){ int r=idx/T, t=idx-r*T; tok_s[r][t]=tokp[(row0+r)*T+t]; }
  }
  if (tid < 8){
    int b = row0 + tid; len_s[tid] = lenp[b];
    if (isCtx){ float s=(float)sstart[b], a=(float)alen[b];
      wins[tid]=s; wine[tid]=s+a-1.0f; winl[tid]=(float)LC - a; }
  }
  for (int idx=tid; idx<2400; idx+=512){ int r=idx/300, d=idx-r*300; hb[0][r][d]=0.f; }
  __syncthreads();
  int maxl=0;
  #pragma unroll
  for (int r=0;r<8;r++) maxl = max(maxl, len_s[r]);

  const int n0=tid, n1=tid+512, n2=tid+1024;
  const bool has3 = tid<176;
  float b0=0.f,b1=0.f,b2=0.f;
  if (fuseX){ b0=bias[n0]; b1=bias[n1]; b2=has3?bias[n2]:0.f; }
  float creg[5];
  #pragma unroll
  for (int s=0;s<5;s++) creg[s]=0.f;
  int cur=0;

  for (int t=0; t<maxl; ++t){
    if (fuseX){
      for (int idx=tid; idx<2400; idx+=512){
        int r=idx/300, d=idx-r*300;
        int L=len_s[r];
        int ts = bwd ? ((t<L)?(L-1-t):t) : t;
        xb[r][d] = embed[(size_t)tok_s[r][ts]*EE + d];
      }
    }
    __syncthreads();

    float a0[8], a1[8], a2[8];
    if (fuseX){
      #pragma unroll
      for (int r=0;r<8;r++){ a0[r]=b0; a1[r]=b1; a2[r]=b2; }
      kloop8(xb, Wi, a0, a1, a2, n0, n1, n2, has3);
    } else {
      #pragma unroll
      for (int r=0;r<8;r++){
        int L=len_s[r];
        if (t < L){
          size_t base = ((size_t)(row0+r)*LC + t)*1200;
          a0[r]=xg[base+n0]; a1[r]=xg[base+n1]; a2[r]=has3?xg[base+n2]:0.f;
        } else { a0[r]=0.f; a1[r]=0.f; a2[r]=0.f; }
      }
    }
    kloop8(hb[cur], Wh, a0, a1, a2, n0, n1, n2, has3);

    #pragma unroll
    for (int r=0;r<8;r++){ gs[r][n0]=a0[r]; gs[r][n1]=a1[r]; if(has3) gs[r][n2]=a2[r]; }
    __syncthreads();

    #pragma unroll
    for (int s=0;s<5;s++){
      int idx = tid + s*512;
      if (idx < 2400){
        int r = idx/300, j = idx - r*300;
        int L = len_s[r];
        if (t < L){
          float gi=gs[r][j], gf=gs[r][300+j], gg=gs[r][600+j], go=gs[r][900+j];
          float cn = sigf(gf)*creg[s] + sigf(gi)*tanhf(gg);
          float hn = sigf(go)*tanhf(cn);
          creg[s]=cn;
          hb[cur^1][r][j]=hn;
          int tpos = bwd ? (L-1-t) : t;
          float wgt = 1.0f;
          if (isCtx){
            float jf=(float)tpos, s_=wins[r], e_=wine[r], sl=winl[r];
            wgt = (jf<s_)?(1.0f-(s_-jf)/sl):((jf<=e_)?0.0f:(1.0f-(jf-e_)/sl));
          }
          outb[((size_t)(row0+r)*T + tpos)*(size_t)D2 + coloff + j] = hn*wgt;
        }
      }
    }
    cur ^= 1;
  }
}

// ---------------- pooling ----------------
__global__ void k_pool(const float* __restrict__ ctx_out, const float* __restrict__ asp_out,
                       const int* __restrict__ clen, const int* __restrict__ alen,
                       float* __restrict__ ctx_pool, float* __restrict__ asp_pool){
  const int b=blockIdx.x; const int tid=threadIdx.x;
  for (int d=tid; d<D2; d+=blockDim.x){
    float s=0.f;
    for (int t=0;t<LC;t++) s+=ctx_out[((size_t)b*LC+t)*D2+d];
    ctx_pool[(size_t)b*D2+d]=s/(float)clen[b];
    float s2=0.f;
    for (int t=0;t<LA;t++) s2+=asp_out[((size_t)b*LA+t)*D2+d];
    asp_pool[(size_t)b*D2+d]=s2/(float)alen[b];
  }
}

// ---------------- v1 = w_a2c @ asp_pool ; v2 = w_c2a @ ctx_pool ----------------
__global__ void k_v1v2(const float* __restrict__ w_a2c, const float* __restrict__ w_c2a,
                       const float* __restrict__ ctx_pool, const float* __restrict__ asp_pool,
                       float* __restrict__ v1, float* __restrict__ v2){
  const int b=blockIdx.x; const int tid=threadIdx.x;
  __shared__ __align__(16) float ap[600];
  __shared__ __align__(16) float cp[600];
  for (int d=tid;d<600;d+=256){ ap[d]=asp_pool[(size_t)b*D2+d]; cp[d]=ctx_pool[(size_t)b*D2+d]; }
  __syncthreads();
  for (int d=tid;d<600;d+=256){
    const float4* ra=(const float4*)(w_a2c+(size_t)d*600);
    const float4* rc=(const float4*)(w_c2a+(size_t)d*600);
    float s1=0.f,s2=0.f;
    for (int e4=0;e4<150;e4++){
      float4 wa=ra[e4], wc=rc[e4];
      const float4 av=*(const float4*)&ap[4*e4];
      const float4 cv=*(const float4*)&cp[4*e4];
      s1 = fmaf(wa.w,av.w,fmaf(wa.z,av.z,fmaf(wa.y,av.y,fmaf(wa.x,av.x,s1))));
      s2 = fmaf(wc.w,cv.w,fmaf(wc.z,cv.z,fmaf(wc.y,cv.y,fmaf(wc.x,cv.x,s2))));
    }
    v1[(size_t)b*D2+d]=s1; v2[(size_t)b*D2+d]=s2;
  }
}

// ---------------- fused attention + head, one block per batch row ----------------
__launch_bounds__(256,2)
__global__ void k_attn(const float* __restrict__ ctx_out, const float* __restrict__ asp_out,
                       const float* __restrict__ v1, const float* __restrict__ v2,
                       const float* __restrict__ w_u, const float* __restrict__ dW,
                       const float* __restrict__ db, float* __restrict__ out)
{
  const int b = blockIdx.x;
  const int tid = threadIdx.x;
  const int wv = tid>>6, lane = tid&63;

  __shared__ float asp[16][600];
  __shared__ float w1s[600], w3s[600], v1s[600], v2s[600];
  __shared__ float u2s[16], m2w[4][16];
  __shared__ float m1s[128], s1s[128];
  __shared__ float alph[128], a1s[128];
  __shared__ float bet[16], a2s[16], m2f[16], s2s[16];
  __shared__ float red[256];
  __shared__ float feat[2400];

  for (int idx=tid; idx<16*600; idx+=256){
    int j=idx/600, d=idx-j*600;
    asp[j][d]=asp_out[((size_t)b*LA+j)*D2+d];
  }
  for (int d=tid; d<600; d+=256){
    w1s[d]=w_u[d]; w3s[d]=w_u[1200+d];
    v1s[d]=v1[(size_t)b*D2+d]; v2s[d]=v2[(size_t)b*D2+d];
  }
  if (tid<64) m2w[tid>>4][tid&15] = -1e30f;
  __syncthreads();
  if (tid<16){
    float s=0.f;
    for (int d=0;d<600;d++) s += asp[tid][d]*w_u[600+d];
    u2s[tid]=s;
  }
  __syncthreads();

  float m2p[16];
  #pragma unroll
  for (int j=0;j<16;j++) m2p[j]=-1e30f;

  for (int i=wv; i<LC; i+=4){
    const float* crow = ctx_out + ((size_t)b*LC+i)*D2;
    float u1p=0.f, s1p=0.f, accj[16];
    #pragma unroll
    for (int j=0;j<16;j++) accj[j]=0.f;
    for (int m=0;m<10;m++){
      int d = lane + m*64;
      if (d<600){
        float v = crow[d];
        u1p = fmaf(v,w1s[d],u1p);
        s1p = fmaf(v,v1s[d],s1p);
        float cw = v*w3s[d];
        #pragma unroll
        for (int j=0;j<16;j++) accj[j] = fmaf(cw,asp[j][d],accj[j]);
      }
    }
    #pragma unroll
    for (int off=32; off>0; off>>=1){
      u1p += __shfl_xor(u1p,off);
      s1p += __shfl_xor(s1p,off);
      #pragma unroll
      for (int j=0;j<16;j++) accj[j] += __shfl_xor(accj[j],off);
    }
    float mj=-1e30f;
    #pragma unroll
    for (int j=0;j<16;j++){
      float a = u2s[j]+accj[j];
      mj = fmaxf(mj,a);
      m2p[j] = fmaxf(m2p[j], u1p+accj[j]);
    }
    if (lane==0){ m1s[i]=u1p+mj; s1s[i]=s1p; }
  }
  if (lane<16) m2w[wv][lane]=m2p[lane];
  __syncthreads();

  {
    float x1 = (tid<128)? m1s[tid] : -1e30f;
    red[tid]=x1; __syncthreads();
    for (int s=128;s>0;s>>=1){ if (tid<s) red[tid]=fmaxf(red[tid],red[tid+s]); __syncthreads(); }
    float M1=red[0]; __syncthreads();
    float e1=(tid<128)?expf(x1-M1):0.f;
    red[tid]=e1; __syncthreads();
    for (int s=128;s>0;s>>=1){ if (tid<s) red[tid]+=red[tid+s]; __syncthreads(); }
    float S1=red[0]; __syncthreads();
    if (tid<128) alph[tid]=e1/S1;

    float x2 = (tid<128)? s1s[tid] : -1e30f;
    red[tid]=x2; __syncthreads();
    for (int s=128;s>0;s>>=1){ if (tid<s) red[tid]=fmaxf(red[tid],red[tid+s]); __syncthreads(); }
    float M2=red[0]; __syncthreads();
    float e2=(tid<128)?expf(x2-M2):0.f;
    red[tid]=e2; __syncthreads();
    for (int s=128;s>0;s>>=1){ if (tid<s) red[tid]+=red[tid+s]; __syncthreads(); }
    float S2=red[0]; __syncthreads();
    if (tid<128) a1s[tid]=e2/S2;
  }

  if (tid<16){
    float m=-1e30f;
    #pragma unroll
    for (int w=0;w<4;w++) m=fmaxf(m,m2w[w][tid]);
    m2f[tid]=u2s[tid]+m;
    float s=0.f;
    for (int d=0;d<600;d++) s = fmaf(asp[tid][d],v2s[d],s);
    s2s[tid]=s;
  }
  __syncthreads();
  if (tid==0){
    float M=-1e30f,S=0.f;
    for (int j=0;j<16;j++) M=fmaxf(M,m2f[j]);
    for (int j=0;j<16;j++){ float e=expf(m2f[j]-M); bet[j]=e; S+=e; }
    for (int j=0;j<16;j++) bet[j]/=S;
    M=-1e30f;S=0.f;
    for (int j=0;j<16;j++) M=fmaxf(M,s2s[j]);
    for (int j=0;j<16;j++){ float e=expf(s2s[j]-M); a2s[j]=e; S+=e; }
    for (int j=0;j<16;j++) a2s[j]/=S;
  }
  __syncthreads();

  {
    const bool has2 = (tid<88);
    float fa0=0,fa1=0,fa2=0, ca0=0,ca1=0,ca2=0;
    for (int i=0;i<LC;i++){
      float al=alph[i], aa=a1s[i];
      const float* crow = ctx_out + ((size_t)b*LC+i)*D2;
      float x0=crow[tid];      fa0=fmaf(al,x0,fa0); ca0=fmaf(aa,x0,ca0);
      float x1=crow[tid+256];  fa1=fmaf(al,x1,fa1); ca1=fmaf(aa,x1,ca1);
      if (has2){ float x2=crow[tid+512]; fa2=fmaf(al,x2,fa2); ca2=fmaf(aa,x2,ca2); }
    }
    feat[tid]=ca0;           feat[600+tid]=fa0;
    feat[tid+256]=ca1;       feat[600+tid+256]=fa1;
    if (has2){ feat[tid+512]=ca2; feat[600+tid+512]=fa2; }

    float fc0=0,fc1=0,fc2=0, cc0=0,cc1=0,cc2=0;
    for (int j=0;j<16;j++){
      float be=bet[j], a2=a2s[j];
      float x0=asp[j][tid];      fc0=fmaf(be,x0,fc0); cc0=fmaf(a2,x0,cc0);
      float x1=asp[j][tid+256];  fc1=fmaf(be,x1,fc1); cc1=fmaf(a2,x1,cc1);
      if (has2){ float x2=asp[j][tid+512]; fc2=fmaf(be,x2,fc2); cc2=fmaf(a2,x2,cc2); }
    }
    feat[1200+tid]=fc0;        feat[1800+tid]=cc0;
    feat[1200+tid+256]=fc1;    feat[1800+tid+256]=cc1;
    if (has2){ feat[1200+tid+512]=fc2; feat[1800+tid+512]=cc2; }
  }
  __syncthreads();

  {
    float p0=0,p1=0,p2=0;
    for (int e=tid;e<2400;e+=256){
      float f=feat[e];
      p0=fmaf(f,dW[e],p0); p1=fmaf(f,dW[2400+e],p1); p2=fmaf(f,dW[4800+e],p2);
    }
    red[tid]=p0; __syncthreads();
    for (int s=128;s>0;s>>=1){ if (tid<s) red[tid]+=red[tid+s]; __syncthreads(); }
    if (tid==0) out[b*3+0]=red[0]+db[0];
    __syncthreads();
    red[tid]=p1; __syncthreads();
    for (int s=128;s>0;s>>=1){ if (tid<s) red[tid]+=red[tid+s]; __syncthreads(); }
    if (tid==0) out[b*3+1]=red[0]+db[1];
    __syncthreads();
    red[tid]=p2; __syncthreads();
    for (int s=128;s>0;s>>=1){ if (tid<s) red[tid]+=red[tid+s]; __syncthreads(); }
    if (tid==0) out[b*3+2]=red[0]+db[2];
  }
}

extern "C" void kernel_launch(void* const* d_in, const int* in_sizes, int n_in,
                              void* d_out, int out_size, void* d_ws, size_t ws_size,
                              hipStream_t stream) {
  const int*   traw =(const int*)d_in[0];
  const int*   tasp =(const int*)d_in[1];
  const int*   tleft=(const int*)d_in[2];
  const float* embed=(const float*)d_in[3];
  const float* cWif=(const float*)d_in[4];
  const float* cWhf=(const float*)d_in[5];
  const float* cbf =(const float*)d_in[6];
  const float* cWib=(const float*)d_in[7];
  const float* cWhb=(const float*)d_in[8];
  const float* cbb =(const float*)d_in[9];
  const float* aWif=(const float*)d_in[10];
  const float* aWhf=(const float*)d_in[11];
  const float* abf =(const float*)d_in[12];
  const float* aWib=(const float*)d_in[13];
  const float* aWhb=(const float*)d_in[14];
  const float* abb =(const float*)d_in[15];
  const float* w_u =(const float*)d_in[16];
  const float* w_a2c=(const float*)d_in[17];
  const float* w_c2a=(const float*)d_in[18];
  const float* dW  =(const float*)d_in[19];
  const float* db  =(const float*)d_in[20];
  float* out = (float*)d_out;

  char* w = (char*)d_ws;
  size_t o = 0;
  float* ctx_out  = (float*)(w+o); o += (size_t)BB*LC*D2*4;   // 157,286,400
  float* asp_out  = (float*)(w+o); o += (size_t)BB*LA*D2*4;   //  19,660,800
  float* WT4      = (float*)(w+o); o += (size_t)8*360000*4;   //  11,520,000
  float* ctx_pool = (float*)(w+o); o += (size_t)BB*D2*4;
  float* asp_pool = (float*)(w+o); o += (size_t)BB*D2*4;
  float* v1       = (float*)(w+o); o += (size_t)BB*D2*4;
  float* v2       = (float*)(w+o); o += (size_t)BB*D2*4;
  int*   clen     = (int*)(w+o);   o += (size_t)BB*4;
  int*   alen_    = (int*)(w+o);   o += (size_t)BB*4;
  int*   sstart   = (int*)(w+o);   o += (size_t)BB*4;
  size_t xg_bytes = (size_t)BB*LC*1200*4;                      // 314,572,800 each
  float* xgcf     = (float*)(w+o);
  float* xgcb     = (float*)(w+o+xg_bytes);
  const int use_xg = (ws_size >= o + 2*xg_bytes) ? 1 : 0;
  if (!use_xg){ xgcf = (float*)w; xgcb = (float*)w; }  // never dereferenced

  hipMemsetAsync(ctx_out, 0, (size_t)BB*LC*D2*4 + (size_t)BB*LA*D2*4, stream);

  k_lengths<<<4,128,0,stream>>>(traw,tasp,tleft,clen,alen_,sstart);
  k_prep<<<dim3(352,1,8),256,0,stream>>>(cWif,cWhf,cWib,cWhb,aWif,aWhf,aWib,aWhb,WT4);
  if (use_xg)
    k_xg<<<512,512,0,stream>>>(traw,embed,WT4,cbf,cbb,clen,xgcf,xgcb);

  k_rec<<<256,512,0,stream>>>(traw,tasp,embed,WT4,
                              cbf,cbb,abf,abb,
                              xgcf,xgcb,
                              clen,alen_,sstart,
                              ctx_out,asp_out,use_xg);

  k_pool<<<512,256,0,stream>>>(ctx_out,asp_out,clen,alen_,ctx_pool,asp_pool);
  k_v1v2<<<512,256,0,stream>>>(w_a2c,w_c2a,ctx_pool,asp_pool,v1,v2);
  k_attn<<<512,256,0,stream>>>(ctx_out,asp_out,v1,v2,w_u,dW,db,out);
}